// Round 7
// baseline (308.289 us; speedup 1.0000x reference)
//
#include <hip/hip_runtime.h>
#include <hip/hip_fp16.h>

#define NN 50000
#define NE 800000
#define DD 64
#define BCAP 64        // bucket capacity per node (Poisson(16): P(>64) ~ 1e-19)
#define OVCAP 4096     // overflow list capacity
#define FG 782         // fill blocks: ceil(NE / (256*4))
#define CG 3125        // tohalf blocks: NN*DD/4 / 256
#define LROW 33        // LDS row stride in u32 (132 B: odd/4 -> conflict-free columns)

typedef unsigned short u16;
typedef unsigned int u32;

// ---- merged prep: bucket fill (atomic-bound) + x->fp16 convert (BW, overlaps) ----
__global__ __launch_bounds__(256) void k_prep(const int* __restrict__ src,
                                              const int* __restrict__ dst,
                                              int* __restrict__ cursor,
                                              u16* __restrict__ bucket,
                                              int* __restrict__ ovn,
                                              int2* __restrict__ ov,
                                              const float* __restrict__ x,
                                              u16* __restrict__ xh) {
    if (blockIdx.x >= FG) {
        int i = (blockIdx.x - FG) * 256 + threadIdx.x;
        if (i < NN * DD / 4) {
            float4 v = ((const float4*)x)[i];
            __half2 h01 = __floats2half2_rn(v.x, v.y);
            __half2 h23 = __floats2half2_rn(v.z, v.w);
            uint2 pk;
            pk.x = *(u32*)&h01; pk.y = *(u32*)&h23;
            ((uint2*)xh)[i] = pk;
        }
        return;
    }
    const int NT = FG * 256;
    int e0 = blockIdx.x * 256 + threadIdx.x;
    int e1 = e0 + NT, e2 = e1 + NT, e3 = e2 + NT;
    int s0 = 0, d0 = 0, s1 = 0, d1 = 0, s2 = 0, d2 = 0, s3 = 0, d3 = 0;
    bool v0 = e0 < NE, v1 = e1 < NE, v2 = e2 < NE, v3 = e3 < NE;
    if (v0) { s0 = src[e0]; d0 = dst[e0]; }
    if (v1) { s1 = src[e1]; d1 = dst[e1]; }
    if (v2) { s2 = src[e2]; d2 = dst[e2]; }
    if (v3) { s3 = src[e3]; d3 = dst[e3]; }
    int p0 = 0, p1 = 0, p2 = 0, p3 = 0;
    if (v0) p0 = atomicAdd(&cursor[d0], 1);
    if (v1) p1 = atomicAdd(&cursor[d1], 1);
    if (v2) p2 = atomicAdd(&cursor[d2], 1);
    if (v3) p3 = atomicAdd(&cursor[d3], 1);
    if (v0) { if (p0 < BCAP) bucket[(size_t)d0 * BCAP + p0] = (u16)s0;
              else { int q = atomicAdd(ovn, 1); if (q < OVCAP) ov[q] = make_int2(d0, s0); } }
    if (v1) { if (p1 < BCAP) bucket[(size_t)d1 * BCAP + p1] = (u16)s1;
              else { int q = atomicAdd(ovn, 1); if (q < OVCAP) ov[q] = make_int2(d1, s1); } }
    if (v2) { if (p2 < BCAP) bucket[(size_t)d2 * BCAP + p2] = (u16)s2;
              else { int q = atomicAdd(ovn, 1); if (q < OVCAP) ov[q] = make_int2(d2, s2); } }
    if (v3) { if (p3 < BCAP) bucket[(size_t)d3 * BCAP + p3] = (u16)s3;
              else { int q = atomicAdd(ovn, 1); if (q < OVCAP) ov[q] = make_int2(d3, s3); } }
}

// accumulate one fp16x4 row chunk (uint2) into 4 scalars, guarded
#define ACC1(U, COND, S0, S1, S2, S3)                                            \
    if (COND) { float2 f0 = __half22float2(*(__half2*)&U.x);                     \
                float2 f1 = __half22float2(*(__half2*)&U.y);                     \
                S0 += f0.x; S1 += f0.y; S2 += f1.x; S3 += f1.y; }

// ---- fused layer: aggregate 64 nodes into fp16 LDS, then dense part from LDS ----
// LAST=0: fp16 out + ReLU | LAST=1: fp32 out, no ReLU
template<int LAST>
__global__ __launch_bounds__(256, 5) void k_layer(const u16* __restrict__ h16,
                                                  const int* __restrict__ cursor,
                                                  const u16* __restrict__ bucket,
                                                  const int* __restrict__ ovn,
                                                  const int2* __restrict__ ov,
                                                  const float* __restrict__ Wl,
                                                  const float* __restrict__ bl,
                                                  const float* __restrict__ Wr,
                                                  u16* __restrict__ out16,
                                                  float* __restrict__ out32)
{
    __shared__ u32 xt[64 * LROW];   // fp16 pairs, row stride 132 B
    __shared__ u32 at[64 * LROW];
    int t = threadIdx.x;
    int r0 = blockIdx.x * 64;
    int wid = t >> 6, l = t & 63, sub = l >> 4, cl = l & 15;

    // ---- stage xt: block's own 64 rows, fp16 verbatim (16B global, 4x4B LDS) ----
    for (int i = t; i < 512; i += 256) {      // 64 rows x 8 chunks of 8 halves
        int r = i >> 3, c8 = i & 7;
        int row = r0 + r;
        uint4 u = make_uint4(0, 0, 0, 0);
        if (row < NN) u = *(const uint4*)(h16 + (size_t)row * DD + c8 * 8);
        u32* p = &xt[r * LROW + c8 * 4];
        p[0] = u.x; p[1] = u.y; p[2] = u.z; p[3] = u.w;
    }

    // ---- phase A: each wave aggregates 16 nodes, 4 concurrently (16 loads/lane) ----
    for (int i = 0; i < 16; i += 4) {
        int rb = wid * 16 + i;
        int n0 = r0 + rb, n1 = n0 + 1, n2 = n0 + 2, n3 = n0 + 3;
        bool v0 = n0 < NN, v1 = n1 < NN, v2 = n2 < NN, v3 = n3 < NN;
        int dg0 = v0 ? cursor[n0] : 0;
        int dg1 = v1 ? cursor[n1] : 0;
        int dg2 = v2 ? cursor[n2] : 0;
        int dg3 = v3 ? cursor[n3] : 0;
        int kk0 = dg0 < BCAP ? dg0 : BCAP;
        int kk1 = dg1 < BCAP ? dg1 : BCAP;
        int kk2 = dg2 < BCAP ? dg2 : BCAP;
        int kk3 = dg3 < BCAP ? dg3 : BCAP;
        int id0 = (l < kk0) ? (int)bucket[(size_t)n0 * BCAP + l] : 0;
        int id1 = (l < kk1) ? (int)bucket[(size_t)n1 * BCAP + l] : 0;
        int id2 = (l < kk2) ? (int)bucket[(size_t)n2 * BCAP + l] : 0;
        int id3 = (l < kk3) ? (int)bucket[(size_t)n3 * BCAP + l] : 0;
        float a00 = 0.f, a01 = 0.f, a02 = 0.f, a03 = 0.f;
        float a10 = 0.f, a11 = 0.f, a12 = 0.f, a13 = 0.f;
        float a20 = 0.f, a21 = 0.f, a22 = 0.f, a23 = 0.f;
        float a30 = 0.f, a31 = 0.f, a32 = 0.f, a33 = 0.f;
        int kmax = kk0 > kk1 ? kk0 : kk1;
        if (kk2 > kmax) kmax = kk2;
        if (kk3 > kmax) kmax = kk3;
        for (int j = 0; j < kmax; j += 16) {
            int p0 = j + sub, p1 = j + 4 + sub, p2 = j + 8 + sub, p3 = j + 12 + sub;
            int b00 = __shfl(id0, p0), b01 = __shfl(id0, p1), b02 = __shfl(id0, p2), b03 = __shfl(id0, p3);
            int b10 = __shfl(id1, p0), b11 = __shfl(id1, p1), b12 = __shfl(id1, p2), b13 = __shfl(id1, p3);
            int b20 = __shfl(id2, p0), b21 = __shfl(id2, p1), b22 = __shfl(id2, p2), b23 = __shfl(id2, p3);
            int b30 = __shfl(id3, p0), b31 = __shfl(id3, p1), b32 = __shfl(id3, p2), b33 = __shfl(id3, p3);
            uint2 u00 = *(const uint2*)(h16 + (size_t)b00 * DD + cl * 4);
            uint2 u01 = *(const uint2*)(h16 + (size_t)b01 * DD + cl * 4);
            uint2 u02 = *(const uint2*)(h16 + (size_t)b02 * DD + cl * 4);
            uint2 u03 = *(const uint2*)(h16 + (size_t)b03 * DD + cl * 4);
            uint2 u10 = *(const uint2*)(h16 + (size_t)b10 * DD + cl * 4);
            uint2 u11 = *(const uint2*)(h16 + (size_t)b11 * DD + cl * 4);
            uint2 u12 = *(const uint2*)(h16 + (size_t)b12 * DD + cl * 4);
            uint2 u13 = *(const uint2*)(h16 + (size_t)b13 * DD + cl * 4);
            uint2 u20 = *(const uint2*)(h16 + (size_t)b20 * DD + cl * 4);
            uint2 u21 = *(const uint2*)(h16 + (size_t)b21 * DD + cl * 4);
            uint2 u22 = *(const uint2*)(h16 + (size_t)b22 * DD + cl * 4);
            uint2 u23 = *(const uint2*)(h16 + (size_t)b23 * DD + cl * 4);
            uint2 u30 = *(const uint2*)(h16 + (size_t)b30 * DD + cl * 4);
            uint2 u31 = *(const uint2*)(h16 + (size_t)b31 * DD + cl * 4);
            uint2 u32v = *(const uint2*)(h16 + (size_t)b32 * DD + cl * 4);
            uint2 u33 = *(const uint2*)(h16 + (size_t)b33 * DD + cl * 4);
            ACC1(u00, p0 < kk0, a00, a01, a02, a03)
            ACC1(u01, p1 < kk0, a00, a01, a02, a03)
            ACC1(u02, p2 < kk0, a00, a01, a02, a03)
            ACC1(u03, p3 < kk0, a00, a01, a02, a03)
            ACC1(u10, p0 < kk1, a10, a11, a12, a13)
            ACC1(u11, p1 < kk1, a10, a11, a12, a13)
            ACC1(u12, p2 < kk1, a10, a11, a12, a13)
            ACC1(u13, p3 < kk1, a10, a11, a12, a13)
            ACC1(u20, p0 < kk2, a20, a21, a22, a23)
            ACC1(u21, p1 < kk2, a20, a21, a22, a23)
            ACC1(u22, p2 < kk2, a20, a21, a22, a23)
            ACC1(u23, p3 < kk2, a20, a21, a22, a23)
            ACC1(u30, p0 < kk3, a30, a31, a32, a33)
            ACC1(u31, p1 < kk3, a30, a31, a32, a33)
            ACC1(u32v, p2 < kk3, a30, a31, a32, a33)
            ACC1(u33, p3 < kk3, a30, a31, a32, a33)
        }

        // overflow contributions (empty in practice -> uniform scalar check)
        int nov = *ovn;
        if (nov > 0) {
            if (nov > OVCAP) nov = OVCAP;
            for (int q = 0; q < nov; q++) {
                int2 p = ov[q];
                bool m0 = (sub == 0) && v0 && (p.x == n0);
                bool m1 = (sub == 1) && v1 && (p.x == n1);
                bool m2 = (sub == 2) && v2 && (p.x == n2);
                bool m3 = (sub == 3) && v3 && (p.x == n3);
                if (m0 | m1 | m2 | m3) {
                    uint2 u = *(const uint2*)(h16 + (size_t)p.y * DD + cl * 4);
                    float2 f0 = __half22float2(*(__half2*)&u.x), f1 = __half22float2(*(__half2*)&u.y);
                    if (m0) { a00 += f0.x; a01 += f0.y; a02 += f1.x; a03 += f1.y; }
                    if (m1) { a10 += f0.x; a11 += f0.y; a12 += f1.x; a13 += f1.y; }
                    if (m2) { a20 += f0.x; a21 += f0.y; a22 += f1.x; a23 += f1.y; }
                    if (m3) { a30 += f0.x; a31 += f0.y; a32 += f1.x; a33 += f1.y; }
                }
            }
        }

        // butterfly across the 4 sub-groups -> every lane holds full sums
        a00 += __shfl_xor(a00, 16); a01 += __shfl_xor(a01, 16);
        a02 += __shfl_xor(a02, 16); a03 += __shfl_xor(a03, 16);
        a00 += __shfl_xor(a00, 32); a01 += __shfl_xor(a01, 32);
        a02 += __shfl_xor(a02, 32); a03 += __shfl_xor(a03, 32);
        a10 += __shfl_xor(a10, 16); a11 += __shfl_xor(a11, 16);
        a12 += __shfl_xor(a12, 16); a13 += __shfl_xor(a13, 16);
        a10 += __shfl_xor(a10, 32); a11 += __shfl_xor(a11, 32);
        a12 += __shfl_xor(a12, 32); a13 += __shfl_xor(a13, 32);
        a20 += __shfl_xor(a20, 16); a21 += __shfl_xor(a21, 16);
        a22 += __shfl_xor(a22, 16); a23 += __shfl_xor(a23, 16);
        a20 += __shfl_xor(a20, 32); a21 += __shfl_xor(a21, 32);
        a22 += __shfl_xor(a22, 32); a23 += __shfl_xor(a23, 32);
        a30 += __shfl_xor(a30, 16); a31 += __shfl_xor(a31, 16);
        a32 += __shfl_xor(a32, 16); a33 += __shfl_xor(a33, 16);
        a30 += __shfl_xor(a30, 32); a31 += __shfl_xor(a31, 32);
        a32 += __shfl_xor(a32, 32); a33 += __shfl_xor(a33, 32);

        // each sub-group writes its node's row (fp16, mean applied)
        {
            float s0, s1, s2, s3; int dg, rr;
            if (sub == 0)      { s0 = a00; s1 = a01; s2 = a02; s3 = a03; dg = dg0; rr = rb; }
            else if (sub == 1) { s0 = a10; s1 = a11; s2 = a12; s3 = a13; dg = dg1; rr = rb + 1; }
            else if (sub == 2) { s0 = a20; s1 = a21; s2 = a22; s3 = a23; dg = dg2; rr = rb + 2; }
            else               { s0 = a30; s1 = a31; s2 = a32; s3 = a33; dg = dg3; rr = rb + 3; }
            float inv = 1.0f / (float)(dg > 1 ? dg : 1);
            __half2 h0 = __floats2half2_rn(s0 * inv, s1 * inv);
            __half2 h1 = __floats2half2_rn(s2 * inv, s3 * inv);
            at[rr * LROW + cl * 2]     = *(u32*)&h0;
            at[rr * LROW + cl * 2 + 1] = *(u32*)&h1;
        }
    }
    __syncthreads();

    // ---- phase B: out = at @ Wl^T + bl + xt @ Wr^T ; W via wave-uniform s_loads ----
    int row = l;
    int j0 = __builtin_amdgcn_readfirstlane(wid * 16);
    float acc[16];
    #pragma unroll
    for (int q = 0; q < 16; q++) acc[q] = bl[j0 + q];

    #pragma unroll 4
    for (int k2 = 0; k2 < 32; k2++) {
        u32 aw = at[row * LROW + k2];
        u32 xw = xt[row * LROW + k2];
        float2 af = __half22float2(*(__half2*)&aw);
        float2 xf = __half22float2(*(__half2*)&xw);
        int k = k2 * 2;
        #pragma unroll
        for (int q = 0; q < 16; q++) {
            acc[q] = fmaf(af.x, Wl[(j0 + q) * DD + k],     acc[q]);
            acc[q] = fmaf(af.y, Wl[(j0 + q) * DD + k + 1], acc[q]);
            acc[q] = fmaf(xf.x, Wr[(j0 + q) * DD + k],     acc[q]);
            acc[q] = fmaf(xf.y, Wr[(j0 + q) * DD + k + 1], acc[q]);
        }
    }

    int grow = r0 + row;
    if (grow < NN) {
        if (LAST == 0) {
            #pragma unroll
            for (int q = 0; q < 16; q++) acc[q] = fmaxf(acc[q], 0.f);
            u32 w[8];
            #pragma unroll
            for (int p = 0; p < 8; p++) {
                __half2 hv = __floats2half2_rn(acc[2 * p], acc[2 * p + 1]);
                w[p] = *(u32*)&hv;
            }
            uint4* dstp = (uint4*)(out16 + (size_t)grow * DD + j0);
            dstp[0] = make_uint4(w[0], w[1], w[2], w[3]);
            dstp[1] = make_uint4(w[4], w[5], w[6], w[7]);
        } else {
            float4* o = (float4*)(out32 + (size_t)grow * DD + j0);
            #pragma unroll
            for (int q4 = 0; q4 < 4; q4++)
                o[q4] = make_float4(acc[q4 * 4 + 0], acc[q4 * 4 + 1],
                                    acc[q4 * 4 + 2], acc[q4 * 4 + 3]);
        }
    }
}

extern "C" void kernel_launch(void* const* d_in, const int* in_sizes, int n_in,
                              void* d_out, int out_size, void* d_ws, size_t ws_size,
                              hipStream_t stream) {
    const float* x   = (const float*)d_in[0];
    const int*   ei  = (const int*)d_in[1];
    const int*   src = ei;            // edge_index[0]
    const int*   dst = ei + NE;       // edge_index[1]
    const float* Wl0 = (const float*)d_in[2];
    const float* bl0 = (const float*)d_in[3];
    const float* Wr0 = (const float*)d_in[4];
    const float* Wl1 = (const float*)d_in[5];
    const float* bl1 = (const float*)d_in[6];
    const float* Wr1 = (const float*)d_in[7];
    const float* Wl2 = (const float*)d_in[8];
    const float* bl2 = (const float*)d_in[9];
    const float* Wr2 = (const float*)d_in[10];
    float* out = (float*)d_out;

    char* ws = (char*)d_ws;
    size_t o = 0;
    u16*   h16A   = (u16*)(ws + o);   o += (size_t)NN * DD * 2;   // 6.4 MB
    u16*   h16B   = (u16*)(ws + o);   o += (size_t)NN * DD * 2;   // 6.4 MB
    u16*   bucket = (u16*)(ws + o);   o += (size_t)NN * BCAP * 2; // 6.4 MB
    int*   cursor = (int*)(ws + o);   o += (size_t)NN * 4;        // 200 KB
    int*   ovn    = (int*)(ws + o);   o += 16;                    // adjacent to cursor
    int2*  ov     = (int2*)(ws + o);  o += (size_t)OVCAP * 8;     // 32 KB

    // ---- prep: zero cursor+ovn, then fill buckets + convert x to fp16 (one launch) ----
    hipMemsetAsync(cursor, 0, (size_t)NN * 4 + 16, stream);
    k_prep<<<FG + CG, 256, 0, stream>>>(src, dst, cursor, bucket, ovn, ov, x, h16B);

    const int gg = (NN + 63) / 64;   // 782

    // layer 0: h16B(x) -> h16A (ReLU)
    k_layer<0><<<gg, 256, 0, stream>>>(h16B, cursor, bucket, ovn, ov, Wl0, bl0, Wr0, h16A, nullptr);
    // layer 1: h16A -> h16B (ReLU)
    k_layer<0><<<gg, 256, 0, stream>>>(h16A, cursor, bucket, ovn, ov, Wl1, bl1, Wr1, h16B, nullptr);
    // layer 2: h16B -> out fp32 (no ReLU)
    k_layer<1><<<gg, 256, 0, stream>>>(h16B, cursor, bucket, ovn, ov, Wl2, bl2, Wr2, nullptr, out);
}

// Round 8
// 191.346 us; speedup vs baseline: 1.6112x; 1.6112x over previous
//
#include <hip/hip_runtime.h>
#include <hip/hip_fp16.h>

#define NN 50000
#define NE 800000
#define DD 64
#define BCAP 64        // bucket capacity per node (Poisson(16): P(>64) ~ 1e-19)
#define OVCAP 4096     // overflow list capacity
#define FG 782         // fill blocks: ceil(NE / (256*4))
#define CG 3125        // tohalf blocks: NN*DD/4 / 256
#define LROW 33        // LDS row stride in u32 (132 B: conflict-free column reads)

typedef unsigned short u16;
typedef unsigned int u32;

// ---- merged prep: bucket fill (atomic-bound) + x->fp16 convert (BW, overlaps) ----
__global__ __launch_bounds__(256) void k_prep(const int* __restrict__ src,
                                              const int* __restrict__ dst,
                                              int* __restrict__ cursor,
                                              u16* __restrict__ bucket,
                                              int* __restrict__ ovn,
                                              int2* __restrict__ ov,
                                              const float* __restrict__ x,
                                              u16* __restrict__ xh) {
    if (blockIdx.x >= FG) {
        int i = (blockIdx.x - FG) * 256 + threadIdx.x;
        if (i < NN * DD / 4) {
            float4 v = ((const float4*)x)[i];
            __half2 h01 = __floats2half2_rn(v.x, v.y);
            __half2 h23 = __floats2half2_rn(v.z, v.w);
            uint2 pk;
            pk.x = *(u32*)&h01; pk.y = *(u32*)&h23;
            ((uint2*)xh)[i] = pk;
        }
        return;
    }
    const int NT = FG * 256;
    int e0 = blockIdx.x * 256 + threadIdx.x;
    int e1 = e0 + NT, e2 = e1 + NT, e3 = e2 + NT;
    int s0 = 0, d0 = 0, s1 = 0, d1 = 0, s2 = 0, d2 = 0, s3 = 0, d3 = 0;
    bool v0 = e0 < NE, v1 = e1 < NE, v2 = e2 < NE, v3 = e3 < NE;
    if (v0) { s0 = src[e0]; d0 = dst[e0]; }
    if (v1) { s1 = src[e1]; d1 = dst[e1]; }
    if (v2) { s2 = src[e2]; d2 = dst[e2]; }
    if (v3) { s3 = src[e3]; d3 = dst[e3]; }
    int p0 = 0, p1 = 0, p2 = 0, p3 = 0;
    if (v0) p0 = atomicAdd(&cursor[d0], 1);
    if (v1) p1 = atomicAdd(&cursor[d1], 1);
    if (v2) p2 = atomicAdd(&cursor[d2], 1);
    if (v3) p3 = atomicAdd(&cursor[d3], 1);
    if (v0) { if (p0 < BCAP) bucket[(size_t)d0 * BCAP + p0] = (u16)s0;
              else { int q = atomicAdd(ovn, 1); if (q < OVCAP) ov[q] = make_int2(d0, s0); } }
    if (v1) { if (p1 < BCAP) bucket[(size_t)d1 * BCAP + p1] = (u16)s1;
              else { int q = atomicAdd(ovn, 1); if (q < OVCAP) ov[q] = make_int2(d1, s1); } }
    if (v2) { if (p2 < BCAP) bucket[(size_t)d2 * BCAP + p2] = (u16)s2;
              else { int q = atomicAdd(ovn, 1); if (q < OVCAP) ov[q] = make_int2(d2, s2); } }
    if (v3) { if (p3 < BCAP) bucket[(size_t)d3 * BCAP + p3] = (u16)s3;
              else { int q = atomicAdd(ovn, 1); if (q < OVCAP) ov[q] = make_int2(d3, s3); } }
}

// ---- standalone gather-aggregate (fp16 in, fp16 out): one wave per node ----
// 4 sub-groups x 16 lanes; 4 independent uint2 loads in flight per lane.
__global__ __launch_bounds__(256) void k_agg(const u16* __restrict__ h16,
                                             const int* __restrict__ cursor,
                                             const u16* __restrict__ bucket,
                                             const int* __restrict__ ovn,
                                             const int2* __restrict__ ov,
                                             u16* __restrict__ agg16) {
    int node = blockIdx.x * 4 + (threadIdx.x >> 6);   // grid covers NN exactly
    int l = threadIdx.x & 63;
    int sub = l >> 4;          // neighbor sub-group 0..3
    int cl = l & 15;           // 4-col block 0..15
    int deg = cursor[node];
    int kk = deg < BCAP ? deg : BCAP;
    int myid = (l < kk) ? (int)bucket[(size_t)node * BCAP + l] : 0;

    float s0 = 0.f, s1 = 0.f, s2 = 0.f, s3 = 0.f;
    for (int j = 0; j < kk; j += 16) {
        int i0 = j + sub, i1 = j + 4 + sub, i2 = j + 8 + sub, i3 = j + 12 + sub;
        int b0 = __shfl(myid, i0);
        int b1 = __shfl(myid, i1);
        int b2 = __shfl(myid, i2);
        int b3 = __shfl(myid, i3);
        uint2 u0 = *(const uint2*)(h16 + (size_t)b0 * DD + cl * 4);
        uint2 u1 = *(const uint2*)(h16 + (size_t)b1 * DD + cl * 4);
        uint2 u2 = *(const uint2*)(h16 + (size_t)b2 * DD + cl * 4);
        uint2 u3 = *(const uint2*)(h16 + (size_t)b3 * DD + cl * 4);
        if (i0 < kk) { float2 f0 = __half22float2(*(__half2*)&u0.x), f1 = __half22float2(*(__half2*)&u0.y);
                       s0 += f0.x; s1 += f0.y; s2 += f1.x; s3 += f1.y; }
        if (i1 < kk) { float2 f0 = __half22float2(*(__half2*)&u1.x), f1 = __half22float2(*(__half2*)&u1.y);
                       s0 += f0.x; s1 += f0.y; s2 += f1.x; s3 += f1.y; }
        if (i2 < kk) { float2 f0 = __half22float2(*(__half2*)&u2.x), f1 = __half22float2(*(__half2*)&u2.y);
                       s0 += f0.x; s1 += f0.y; s2 += f1.x; s3 += f1.y; }
        if (i3 < kk) { float2 f0 = __half22float2(*(__half2*)&u3.x), f1 = __half22float2(*(__half2*)&u3.y);
                       s0 += f0.x; s1 += f0.y; s2 += f1.x; s3 += f1.y; }
    }

    // overflow contributions (empty in practice -> one uniform scalar check)
    int nov = *ovn;
    if (nov > 0 && sub == 0) {
        if (nov > OVCAP) nov = OVCAP;
        for (int i = 0; i < nov; i++) {
            int2 p = ov[i];
            if (p.x == node) {
                uint2 u = *(const uint2*)(h16 + (size_t)p.y * DD + cl * 4);
                float2 f0 = __half22float2(*(__half2*)&u.x), f1 = __half22float2(*(__half2*)&u.y);
                s0 += f0.x; s1 += f0.y; s2 += f1.x; s3 += f1.y;
            }
        }
    }

    // butterfly across the 4 sub-groups
    s0 += __shfl_xor(s0, 16); s1 += __shfl_xor(s1, 16);
    s2 += __shfl_xor(s2, 16); s3 += __shfl_xor(s3, 16);
    s0 += __shfl_xor(s0, 32); s1 += __shfl_xor(s1, 32);
    s2 += __shfl_xor(s2, 32); s3 += __shfl_xor(s3, 32);

    if (sub == 0) {
        float inv = 1.0f / (float)(deg > 1 ? deg : 1);
        __half2 h0 = __floats2half2_rn(s0 * inv, s1 * inv);
        __half2 h1 = __floats2half2_rn(s2 * inv, s3 * inv);
        uint2 pk; pk.x = *(u32*)&h0; pk.y = *(u32*)&h1;
        *(uint2*)(agg16 + (size_t)node * DD + cl * 4) = pk;
    }
}

// ---- dense part: out = agg @ Wl^T + bl + h @ Wr^T (+ReLU) ----
// 512 threads = 8 waves per 64-row block; wave -> 8 cols (j0 wave-uniform ->
// W and bias ride the scalar pipe; zero LDS for W). fp16 LDS tiles.
// LAST=0: fp16 out + ReLU | LAST=1: fp32 out, no ReLU
template<int LAST>
__global__ __launch_bounds__(512) void k_gemm(const u16* __restrict__ h16,
                                              const u16* __restrict__ agg16,
                                              const float* __restrict__ Wl,
                                              const float* __restrict__ bl,
                                              const float* __restrict__ Wr,
                                              u16* __restrict__ out16,
                                              float* __restrict__ out32)
{
    __shared__ u32 xt[64 * LROW];   // fp16 pairs, row stride 132 B
    __shared__ u32 at[64 * LROW];
    int t = threadIdx.x;
    int r0 = blockIdx.x * 64;

    // stage both tiles: 512 threads x one uint4 (8 halves) each
    {
        int r = t >> 3, c8 = t & 7;
        int row = r0 + r;
        uint4 ux = make_uint4(0, 0, 0, 0), ua = ux;
        if (row < NN) {
            ux = *(const uint4*)(h16  + (size_t)row * DD + c8 * 8);
            ua = *(const uint4*)(agg16 + (size_t)row * DD + c8 * 8);
        }
        u32* px = &xt[r * LROW + c8 * 4];
        px[0] = ux.x; px[1] = ux.y; px[2] = ux.z; px[3] = ux.w;
        u32* pa = &at[r * LROW + c8 * 4];
        pa[0] = ua.x; pa[1] = ua.y; pa[2] = ua.z; pa[3] = ua.w;
    }
    __syncthreads();

    int row = t & 63;
    int j0 = __builtin_amdgcn_readfirstlane((t >> 6) * 8);   // wave-uniform SGPR
    float acc[8];
    #pragma unroll
    for (int q = 0; q < 8; q++) acc[q] = bl[j0 + q];

    #pragma unroll 4
    for (int k2 = 0; k2 < 32; k2++) {
        u32 aw = at[row * LROW + k2];
        u32 xw = xt[row * LROW + k2];
        float2 af = __half22float2(*(__half2*)&aw);
        float2 xf = __half22float2(*(__half2*)&xw);
        int k = k2 * 2;
        #pragma unroll
        for (int q = 0; q < 8; q++) {
            acc[q] = fmaf(af.x, Wl[(j0 + q) * DD + k],     acc[q]);
            acc[q] = fmaf(af.y, Wl[(j0 + q) * DD + k + 1], acc[q]);
            acc[q] = fmaf(xf.x, Wr[(j0 + q) * DD + k],     acc[q]);
            acc[q] = fmaf(xf.y, Wr[(j0 + q) * DD + k + 1], acc[q]);
        }
    }

    int grow = r0 + row;
    if (grow < NN) {
        if (LAST == 0) {
            #pragma unroll
            for (int q = 0; q < 8; q++) acc[q] = fmaxf(acc[q], 0.f);
            u32 w[4];
            #pragma unroll
            for (int p = 0; p < 4; p++) {
                __half2 hv = __floats2half2_rn(acc[2 * p], acc[2 * p + 1]);
                w[p] = *(u32*)&hv;
            }
            *(uint4*)(out16 + (size_t)grow * DD + j0) = make_uint4(w[0], w[1], w[2], w[3]);
        } else {
            float4* o = (float4*)(out32 + (size_t)grow * DD + j0);
            o[0] = make_float4(acc[0], acc[1], acc[2], acc[3]);
            o[1] = make_float4(acc[4], acc[5], acc[6], acc[7]);
        }
    }
}

extern "C" void kernel_launch(void* const* d_in, const int* in_sizes, int n_in,
                              void* d_out, int out_size, void* d_ws, size_t ws_size,
                              hipStream_t stream) {
    const float* x   = (const float*)d_in[0];
    const int*   ei  = (const int*)d_in[1];
    const int*   src = ei;            // edge_index[0]
    const int*   dst = ei + NE;       // edge_index[1]
    const float* Wl0 = (const float*)d_in[2];
    const float* bl0 = (const float*)d_in[3];
    const float* Wr0 = (const float*)d_in[4];
    const float* Wl1 = (const float*)d_in[5];
    const float* bl1 = (const float*)d_in[6];
    const float* Wr1 = (const float*)d_in[7];
    const float* Wl2 = (const float*)d_in[8];
    const float* bl2 = (const float*)d_in[9];
    const float* Wr2 = (const float*)d_in[10];
    float* out = (float*)d_out;

    char* ws = (char*)d_ws;
    size_t o = 0;
    u16*   h16A   = (u16*)(ws + o);   o += (size_t)NN * DD * 2;   // 6.4 MB
    u16*   h16B   = (u16*)(ws + o);   o += (size_t)NN * DD * 2;   // 6.4 MB
    u16*   agg16  = (u16*)(ws + o);   o += (size_t)NN * DD * 2;   // 6.4 MB
    u16*   bucket = (u16*)(ws + o);   o += (size_t)NN * BCAP * 2; // 6.4 MB
    int*   cursor = (int*)(ws + o);   o += (size_t)NN * 4;        // 200 KB
    int*   ovn    = (int*)(ws + o);   o += 16;                    // adjacent to cursor
    int2*  ov     = (int2*)(ws + o);  o += (size_t)OVCAP * 8;     // 32 KB

    // ---- prep: zero cursor+ovn, then fill buckets + convert x to fp16 (one launch) ----
    hipMemsetAsync(cursor, 0, (size_t)NN * 4 + 16, stream);
    k_prep<<<FG + CG, 256, 0, stream>>>(src, dst, cursor, bucket, ovn, ov, x, h16B);

    const int ag = NN / 4;           // 12500: one wave per node
    const int gg = (NN + 63) / 64;   // 782

    // layer 0: h16B(x) -> h16A (ReLU)
    k_agg<<<ag, 256, 0, stream>>>(h16B, cursor, bucket, ovn, ov, agg16);
    k_gemm<0><<<gg, 512, 0, stream>>>(h16B, agg16, Wl0, bl0, Wr0, h16A, nullptr);
    // layer 1: h16A -> h16B (ReLU)
    k_agg<<<ag, 256, 0, stream>>>(h16A, cursor, bucket, ovn, ov, agg16);
    k_gemm<0><<<gg, 512, 0, stream>>>(h16A, agg16, Wl1, bl1, Wr1, h16B, nullptr);
    // layer 2: h16B -> out fp32 (no ReLU)
    k_agg<<<ag, 256, 0, stream>>>(h16B, cursor, bucket, ovn, ov, agg16);
    k_gemm<1><<<gg, 512, 0, stream>>>(h16B, agg16, Wl2, bl2, Wr2, nullptr, out);
}

// Round 9
// 181.851 us; speedup vs baseline: 1.6953x; 1.0522x over previous
//
#include <hip/hip_runtime.h>
#include <hip/hip_fp16.h>

#define NN 50000
#define NE 800000
#define DD 64
#define BCAP 64        // bucket capacity per node (Poisson(16): P(>64) ~ 1e-19)
#define OVCAP 4096     // overflow list capacity
#define NBINS 782      // ceil(NN/64): bin = dst >> 6 (64 nodes per bin)
#define SEGCAP 1536    // per-bin segment capacity (Poisson(1024) + 15 sigma)
#define PB 98          // partition blocks: ceil(NE / 8192)
#define EPB 8192       // edges per partition block
#define CG 3125        // tohalf blocks: NN*DD/4 / 256
#define LROW 33        // LDS row stride in u32 (132 B: conflict-free column reads)

typedef unsigned short u16;
typedef unsigned int u32;

// ---- P2: partition edges into 64-node bins via LDS histogram + chunk reservation.
//      Extra blocks (>= PB) convert x -> fp16 (independent, overlaps). ----
__global__ __launch_bounds__(256) void k_part(const int* __restrict__ src,
                                              const int* __restrict__ dst,
                                              int* __restrict__ seg_cnt,
                                              u32* __restrict__ sorted,
                                              int* __restrict__ ovn,
                                              int2* __restrict__ ov,
                                              const float* __restrict__ x,
                                              u16* __restrict__ xh) {
    if (blockIdx.x >= PB) {
        int i = (blockIdx.x - PB) * 256 + threadIdx.x;
        if (i < NN * DD / 4) {
            float4 v = ((const float4*)x)[i];
            __half2 h01 = __floats2half2_rn(v.x, v.y);
            __half2 h23 = __floats2half2_rn(v.z, v.w);
            uint2 pk;
            pk.x = *(u32*)&h01; pk.y = *(u32*)&h23;
            ((uint2*)xh)[i] = pk;
        }
        return;
    }
    __shared__ int hist[NBINS];
    int t = threadIdx.x;
    int base_e = blockIdx.x * EPB;
    for (int i = t; i < NBINS; i += 256) hist[i] = 0;
    __syncthreads();
    // pass A: block-local histogram (coalesced dst reads, LDS atomics)
    #pragma unroll 4
    for (int r = 0; r < EPB / 256; r++) {
        int e = base_e + r * 256 + t;
        if (e < NE) atomicAdd(&hist[dst[e] >> 6], 1);
    }
    __syncthreads();
    // reserve one contiguous chunk per non-empty bin (one global atomic each)
    for (int i = t; i < NBINS; i += 256) {
        int c = hist[i];
        int b = (c > 0) ? atomicAdd(&seg_cnt[i], c) : 0;
        hist[i] = b;    // segment-relative base for this block's chunk
    }
    __syncthreads();
    // pass B: scatter edges into reserved chunks (LDS cursor, contiguous runs)
    #pragma unroll 4
    for (int r = 0; r < EPB / 256; r++) {
        int e = base_e + r * 256 + t;
        if (e < NE) {
            int d = dst[e], s = src[e];
            int bin = d >> 6;
            int pos = atomicAdd(&hist[bin], 1);
            if (pos < SEGCAP) sorted[bin * SEGCAP + pos] = ((u32)(d & 63) << 16) | (u32)s;
            else { int q = atomicAdd(ovn, 1); if (q < OVCAP) ov[q] = make_int2(d, s); }
        }
    }
}

// ---- P4: per-bin bucket build. Contiguous segment read, LDS slot cursor,
//      localized bucket writes (8 KB node-region per block), degree output. ----
__global__ __launch_bounds__(256) void k_bucket(const int* __restrict__ seg_cnt,
                                                const u32* __restrict__ sorted,
                                                u16* __restrict__ bucket,
                                                int* __restrict__ deg,
                                                int* __restrict__ ovn,
                                                int2* __restrict__ ov) {
    int bin = blockIdx.x;
    int t = threadIdx.x;
    __shared__ int cur[64];
    if (t < 64) cur[t] = 0;
    __syncthreads();
    int n = seg_cnt[bin];
    if (n > SEGCAP) n = SEGCAP;
    for (int i = t; i < n; i += 256) {
        u32 w = sorted[bin * SEGCAP + i];
        int dl = (int)(w >> 16);
        int s  = (int)(w & 0xFFFF);
        int slot = atomicAdd(&cur[dl], 1);
        int node = (bin << 6) + dl;
        if (slot < BCAP) bucket[(size_t)node * BCAP + slot] = (u16)s;
        else { int q = atomicAdd(ovn, 1); if (q < OVCAP) ov[q] = make_int2(node, s); }
    }
    __syncthreads();
    if (t < 64) {
        int node = (bin << 6) + t;
        if (node < NN) deg[node] = cur[t];
    }
}

// ---- standalone gather-aggregate (fp16 in, fp16 out): one wave per node ----
// 4 sub-groups x 16 lanes; 4 independent uint2 loads in flight per lane.
__global__ __launch_bounds__(256) void k_agg(const u16* __restrict__ h16,
                                             const int* __restrict__ deg_arr,
                                             const u16* __restrict__ bucket,
                                             const int* __restrict__ ovn,
                                             const int2* __restrict__ ov,
                                             u16* __restrict__ agg16) {
    int node = blockIdx.x * 4 + (threadIdx.x >> 6);   // grid covers NN exactly
    int l = threadIdx.x & 63;
    int sub = l >> 4;          // neighbor sub-group 0..3
    int cl = l & 15;           // 4-col block 0..15
    int deg = deg_arr[node];
    int kk = deg < BCAP ? deg : BCAP;
    int myid = (l < kk) ? (int)bucket[(size_t)node * BCAP + l] : 0;

    float s0 = 0.f, s1 = 0.f, s2 = 0.f, s3 = 0.f;
    for (int j = 0; j < kk; j += 16) {
        int i0 = j + sub, i1 = j + 4 + sub, i2 = j + 8 + sub, i3 = j + 12 + sub;
        int b0 = __shfl(myid, i0);
        int b1 = __shfl(myid, i1);
        int b2 = __shfl(myid, i2);
        int b3 = __shfl(myid, i3);
        uint2 u0 = *(const uint2*)(h16 + (size_t)b0 * DD + cl * 4);
        uint2 u1 = *(const uint2*)(h16 + (size_t)b1 * DD + cl * 4);
        uint2 u2 = *(const uint2*)(h16 + (size_t)b2 * DD + cl * 4);
        uint2 u3 = *(const uint2*)(h16 + (size_t)b3 * DD + cl * 4);
        if (i0 < kk) { float2 f0 = __half22float2(*(__half2*)&u0.x), f1 = __half22float2(*(__half2*)&u0.y);
                       s0 += f0.x; s1 += f0.y; s2 += f1.x; s3 += f1.y; }
        if (i1 < kk) { float2 f0 = __half22float2(*(__half2*)&u1.x), f1 = __half22float2(*(__half2*)&u1.y);
                       s0 += f0.x; s1 += f0.y; s2 += f1.x; s3 += f1.y; }
        if (i2 < kk) { float2 f0 = __half22float2(*(__half2*)&u2.x), f1 = __half22float2(*(__half2*)&u2.y);
                       s0 += f0.x; s1 += f0.y; s2 += f1.x; s3 += f1.y; }
        if (i3 < kk) { float2 f0 = __half22float2(*(__half2*)&u3.x), f1 = __half22float2(*(__half2*)&u3.y);
                       s0 += f0.x; s1 += f0.y; s2 += f1.x; s3 += f1.y; }
    }

    // overflow contributions (empty in practice -> one uniform scalar check)
    int nov = *ovn;
    if (nov > 0 && sub == 0) {
        if (nov > OVCAP) nov = OVCAP;
        for (int i = 0; i < nov; i++) {
            int2 p = ov[i];
            if (p.x == node) {
                uint2 u = *(const uint2*)(h16 + (size_t)p.y * DD + cl * 4);
                float2 f0 = __half22float2(*(__half2*)&u.x), f1 = __half22float2(*(__half2*)&u.y);
                s0 += f0.x; s1 += f0.y; s2 += f1.x; s3 += f1.y;
            }
        }
    }

    // butterfly across the 4 sub-groups
    s0 += __shfl_xor(s0, 16); s1 += __shfl_xor(s1, 16);
    s2 += __shfl_xor(s2, 16); s3 += __shfl_xor(s3, 16);
    s0 += __shfl_xor(s0, 32); s1 += __shfl_xor(s1, 32);
    s2 += __shfl_xor(s2, 32); s3 += __shfl_xor(s3, 32);

    if (sub == 0) {
        float inv = 1.0f / (float)(deg > 1 ? deg : 1);
        __half2 h0 = __floats2half2_rn(s0 * inv, s1 * inv);
        __half2 h1 = __floats2half2_rn(s2 * inv, s3 * inv);
        uint2 pk; pk.x = *(u32*)&h0; pk.y = *(u32*)&h1;
        *(uint2*)(agg16 + (size_t)node * DD + cl * 4) = pk;
    }
}

// ---- dense part: out = agg @ Wl^T + bl + h @ Wr^T (+ReLU) ----
// 512 threads = 8 waves per 64-row block; j0 wave-uniform -> W/bias on the
// scalar pipe; zero LDS for W. fp16 LDS tiles (17 KB).
// LAST=0: fp16 out + ReLU | LAST=1: fp32 out, no ReLU
template<int LAST>
__global__ __launch_bounds__(512) void k_gemm(const u16* __restrict__ h16,
                                              const u16* __restrict__ agg16,
                                              const float* __restrict__ Wl,
                                              const float* __restrict__ bl,
                                              const float* __restrict__ Wr,
                                              u16* __restrict__ out16,
                                              float* __restrict__ out32)
{
    __shared__ u32 xt[64 * LROW];   // fp16 pairs, row stride 132 B
    __shared__ u32 at[64 * LROW];
    int t = threadIdx.x;
    int r0 = blockIdx.x * 64;

    // stage both tiles: 512 threads x one uint4 (8 halves) each
    {
        int r = t >> 3, c8 = t & 7;
        int row = r0 + r;
        uint4 ux = make_uint4(0, 0, 0, 0), ua = ux;
        if (row < NN) {
            ux = *(const uint4*)(h16  + (size_t)row * DD + c8 * 8);
            ua = *(const uint4*)(agg16 + (size_t)row * DD + c8 * 8);
        }
        u32* px = &xt[r * LROW + c8 * 4];
        px[0] = ux.x; px[1] = ux.y; px[2] = ux.z; px[3] = ux.w;
        u32* pa = &at[r * LROW + c8 * 4];
        pa[0] = ua.x; pa[1] = ua.y; pa[2] = ua.z; pa[3] = ua.w;
    }
    __syncthreads();

    int row = t & 63;
    int j0 = __builtin_amdgcn_readfirstlane((t >> 6) * 8);   // wave-uniform SGPR
    float acc[8];
    #pragma unroll
    for (int q = 0; q < 8; q++) acc[q] = bl[j0 + q];

    #pragma unroll 4
    for (int k2 = 0; k2 < 32; k2++) {
        u32 aw = at[row * LROW + k2];
        u32 xw = xt[row * LROW + k2];
        float2 af = __half22float2(*(__half2*)&aw);
        float2 xf = __half22float2(*(__half2*)&xw);
        int k = k2 * 2;
        #pragma unroll
        for (int q = 0; q < 8; q++) {
            acc[q] = fmaf(af.x, Wl[(j0 + q) * DD + k],     acc[q]);
            acc[q] = fmaf(af.y, Wl[(j0 + q) * DD + k + 1], acc[q]);
            acc[q] = fmaf(xf.x, Wr[(j0 + q) * DD + k],     acc[q]);
            acc[q] = fmaf(xf.y, Wr[(j0 + q) * DD + k + 1], acc[q]);
        }
    }

    int grow = r0 + row;
    if (grow < NN) {
        if (LAST == 0) {
            #pragma unroll
            for (int q = 0; q < 8; q++) acc[q] = fmaxf(acc[q], 0.f);
            u32 w[4];
            #pragma unroll
            for (int p = 0; p < 4; p++) {
                __half2 hv = __floats2half2_rn(acc[2 * p], acc[2 * p + 1]);
                w[p] = *(u32*)&hv;
            }
            *(uint4*)(out16 + (size_t)grow * DD + j0) = make_uint4(w[0], w[1], w[2], w[3]);
        } else {
            float4* o = (float4*)(out32 + (size_t)grow * DD + j0);
            o[0] = make_float4(acc[0], acc[1], acc[2], acc[3]);
            o[1] = make_float4(acc[4], acc[5], acc[6], acc[7]);
        }
    }
}

extern "C" void kernel_launch(void* const* d_in, const int* in_sizes, int n_in,
                              void* d_out, int out_size, void* d_ws, size_t ws_size,
                              hipStream_t stream) {
    const float* x   = (const float*)d_in[0];
    const int*   ei  = (const int*)d_in[1];
    const int*   src = ei;            // edge_index[0]
    const int*   dst = ei + NE;       // edge_index[1]
    const float* Wl0 = (const float*)d_in[2];
    const float* bl0 = (const float*)d_in[3];
    const float* Wr0 = (const float*)d_in[4];
    const float* Wl1 = (const float*)d_in[5];
    const float* bl1 = (const float*)d_in[6];
    const float* Wr1 = (const float*)d_in[7];
    const float* Wl2 = (const float*)d_in[8];
    const float* bl2 = (const float*)d_in[9];
    const float* Wr2 = (const float*)d_in[10];
    float* out = (float*)d_out;

    char* ws = (char*)d_ws;
    size_t o = 0;
    u16*   h16A   = (u16*)(ws + o);   o += (size_t)NN * DD * 2;        // 6.4 MB
    u16*   h16B   = (u16*)(ws + o);   o += (size_t)NN * DD * 2;        // 6.4 MB
    u16*   agg16  = (u16*)(ws + o);   o += (size_t)NN * DD * 2;        // 6.4 MB
    u16*   bucket = (u16*)(ws + o);   o += (size_t)NN * BCAP * 2;      // 6.4 MB
    u32*   sorted = (u32*)(ws + o);   o += (size_t)NBINS * SEGCAP * 4; // 4.8 MB
    int*   deg    = (int*)(ws + o);   o += (size_t)NN * 4;             // 200 KB
    int*   seg_cnt= (int*)(ws + o);   o += (size_t)NBINS * 4;          // 3.1 KB
    int*   ovn    = (int*)(ws + o);   o += 16;                         // adjacent to seg_cnt
    int2*  ov     = (int2*)(ws + o);  o += (size_t)OVCAP * 8;          // 32 KB

    // ---- prep: zero seg_cnt+ovn; partition edges; build buckets (dst invariant) ----
    hipMemsetAsync(seg_cnt, 0, (size_t)NBINS * 4 + 16, stream);
    k_part<<<PB + CG, 256, 0, stream>>>(src, dst, seg_cnt, sorted, ovn, ov, x, h16B);
    k_bucket<<<NBINS, 256, 0, stream>>>(seg_cnt, sorted, bucket, deg, ovn, ov);

    const int ag = NN / 4;           // 12500: one wave per node
    const int gg = (NN + 63) / 64;   // 782

    // layer 0: h16B(x) -> h16A (ReLU)
    k_agg<<<ag, 256, 0, stream>>>(h16B, deg, bucket, ovn, ov, agg16);
    k_gemm<0><<<gg, 512, 0, stream>>>(h16B, agg16, Wl0, bl0, Wr0, h16A, nullptr);
    // layer 1: h16A -> h16B (ReLU)
    k_agg<<<ag, 256, 0, stream>>>(h16A, deg, bucket, ovn, ov, agg16);
    k_gemm<0><<<gg, 512, 0, stream>>>(h16A, agg16, Wl1, bl1, Wr1, h16B, nullptr);
    // layer 2: h16B -> out fp32 (no ReLU)
    k_agg<<<ag, 256, 0, stream>>>(h16B, deg, bucket, ovn, ov, agg16);
    k_gemm<1><<<gg, 512, 0, stream>>>(h16B, agg16, Wl2, bl2, Wr2, nullptr, out);
}

// Round 12
// 133.838 us; speedup vs baseline: 2.3035x; 1.3587x over previous
//
#include <hip/hip_runtime.h>
#include <hip/hip_fp16.h>

#define NN 50000
#define NE 800000
#define DD 64
#define BCAP 64        // bucket capacity per node (Poisson(16): P(>64) ~ 1e-19)
#define OVCAP 4096     // overflow list capacity
#define NBINS 196      // ceil(NN/256): bin = dst >> 8 (256 nodes per bin)
#define SEGCAP 4608    // per-bin segment capacity (mean 4082 + ~8 sigma)
#define PB 391         // partition blocks: ceil(NE / 2048)
#define EPB 2048       // edges per partition block
#define WB 12          // W fp16-pack blocks (6 mats x 2048 u32 / (256*4))
#define CG 3125        // tohalf blocks: NN*DD/4 / 256
#define LROW 33        // LDS row stride in u32 (132 B: conflict-free column reads)
#define SEGPAD 16      // seg_cnt stride in ints (one 64B line per bin)

typedef unsigned short u16;
typedef unsigned int u32;

// packed fp16x2 dot with f32 accumulate; hardware v_dot2_f32_f16 when available
__device__ __forceinline__ float dot2(u32 a, u32 b, float c) {
#if __has_builtin(__builtin_amdgcn_fdot2)
    typedef _Float16 h2 __attribute__((ext_vector_type(2)));
    h2 av, bv;
    __builtin_memcpy(&av, &a, 4);
    __builtin_memcpy(&bv, &b, 4);
    return __builtin_amdgcn_fdot2(av, bv, c, false);
#else
    float2 af = __half22float2(*(__half2*)&a);
    float2 bf = __half22float2(*(__half2*)&b);
    return fmaf(af.x, bf.x, fmaf(af.y, bf.y, c));
#endif
}

// ---- P2: partition edges into 256-node bins via LDS histogram + line-padded
//      chunk reservation. Extra blocks: W fp16-pack, then x -> fp16 convert. ----
__global__ __launch_bounds__(256) void k_part(const int* __restrict__ src,
                                              const int* __restrict__ dst,
                                              int* __restrict__ seg_cnt,
                                              u32* __restrict__ sorted,
                                              int* __restrict__ ovn,
                                              int2* __restrict__ ov,
                                              const float* __restrict__ x,
                                              u16* __restrict__ xh,
                                              const float* __restrict__ Wl0,
                                              const float* __restrict__ Wr0,
                                              const float* __restrict__ Wl1,
                                              const float* __restrict__ Wr1,
                                              const float* __restrict__ Wl2,
                                              const float* __restrict__ Wr2,
                                              u32* __restrict__ Wh) {
    int t = threadIdx.x;
    if (blockIdx.x >= PB + WB) {              // ---- x -> fp16 convert ----
        int i = (blockIdx.x - PB - WB) * 256 + t;
        if (i < NN * DD / 4) {
            float4 v = ((const float4*)x)[i];
            __half2 h01 = __floats2half2_rn(v.x, v.y);
            __half2 h23 = __floats2half2_rn(v.z, v.w);
            uint2 pk;
            pk.x = *(u32*)&h01; pk.y = *(u32*)&h23;
            ((uint2*)xh)[i] = pk;
        }
        return;
    }
    if (blockIdx.x >= PB) {                   // ---- W fp32 -> packed fp16 pairs ----
        int widx = (blockIdx.x - PB) * 256 + t;
        #pragma unroll
        for (int r = 0; r < 4; r++) {
            int oi = widx + r * (WB * 256);
            if (oi < 6 * 2048) {
                int mat = oi >> 11, rem = oi & 2047;
                const float* Wsrc;
                switch (mat) {
                    case 0: Wsrc = Wl0; break;
                    case 1: Wsrc = Wr0; break;
                    case 2: Wsrc = Wl1; break;
                    case 3: Wsrc = Wr1; break;
                    case 4: Wsrc = Wl2; break;
                    default: Wsrc = Wr2; break;
                }
                __half2 hv = __floats2half2_rn(Wsrc[rem * 2], Wsrc[rem * 2 + 1]);
                Wh[oi] = *(u32*)&hv;
            }
        }
        return;
    }
    // ---- edge partition ----
    __shared__ int hist[NBINS];
    int base_e = blockIdx.x * EPB;
    if (t < NBINS) hist[t] = 0;
    __syncthreads();
    #pragma unroll 4
    for (int r = 0; r < EPB / 256; r++) {     // pass A: block-local histogram
        int e = base_e + r * 256 + t;
        if (e < NE) atomicAdd(&hist[dst[e] >> 8], 1);
    }
    __syncthreads();
    if (t < NBINS) {                          // reserve chunk (1 line per bin)
        int c = hist[t];
        int b = (c > 0) ? atomicAdd(&seg_cnt[t * SEGPAD], c) : 0;
        hist[t] = b;
    }
    __syncthreads();
    #pragma unroll 4
    for (int r = 0; r < EPB / 256; r++) {     // pass B: scatter into chunks
        int e = base_e + r * 256 + t;
        if (e < NE) {
            int d = dst[e], s = src[e];
            int bin = d >> 8;
            int pos = atomicAdd(&hist[bin], 1);
            if (pos < SEGCAP) sorted[bin * SEGCAP + pos] = ((u32)(d & 255) << 16) | (u32)s;
            else { int q = atomicAdd(ovn, 1); if (q < OVCAP) ov[q] = make_int2(d, s); }
        }
    }
}

// ---- P4: per-bin bucket build. Contiguous segment read, 256-node LDS cursor,
//      localized bucket writes (32 KB node-region per block), degree output. ----
__global__ __launch_bounds__(256) void k_bucket(const int* __restrict__ seg_cnt,
                                                const u32* __restrict__ sorted,
                                                u16* __restrict__ bucket,
                                                int* __restrict__ deg,
                                                int* __restrict__ ovn,
                                                int2* __restrict__ ov) {
    int bin = blockIdx.x;
    int t = threadIdx.x;
    __shared__ int cur[256];
    cur[t] = 0;
    __syncthreads();
    int n = seg_cnt[bin * SEGPAD];
    if (n > SEGCAP) n = SEGCAP;
    for (int i = t; i < n; i += 256) {
        u32 w = sorted[bin * SEGCAP + i];
        int dl = (int)(w >> 16);
        int s  = (int)(w & 0xFFFF);
        int slot = atomicAdd(&cur[dl], 1);
        int node = (bin << 8) + dl;
        if (slot < BCAP) bucket[(size_t)node * BCAP + slot] = (u16)s;
        else { int q = atomicAdd(ovn, 1); if (q < OVCAP) ov[q] = make_int2(node, s); }
    }
    __syncthreads();
    int node = (bin << 8) + t;
    if (node < NN) deg[node] = cur[t];
}

// ---- standalone gather-aggregate (fp16 in, fp16 out): one wave per node ----
__global__ __launch_bounds__(256) void k_agg(const u16* __restrict__ h16,
                                             const int* __restrict__ deg_arr,
                                             const u16* __restrict__ bucket,
                                             const int* __restrict__ ovn,
                                             const int2* __restrict__ ov,
                                             u16* __restrict__ agg16) {
    int node = blockIdx.x * 4 + (threadIdx.x >> 6);   // grid covers NN exactly
    int l = threadIdx.x & 63;
    int sub = l >> 4;          // neighbor sub-group 0..3
    int cl = l & 15;           // 4-col block 0..15
    int deg = deg_arr[node];
    int kk = deg < BCAP ? deg : BCAP;
    int myid = (l < kk) ? (int)bucket[(size_t)node * BCAP + l] : 0;

    float s0 = 0.f, s1 = 0.f, s2 = 0.f, s3 = 0.f;
    for (int j = 0; j < kk; j += 16) {
        int i0 = j + sub, i1 = j + 4 + sub, i2 = j + 8 + sub, i3 = j + 12 + sub;
        int b0 = __shfl(myid, i0);
        int b1 = __shfl(myid, i1);
        int b2 = __shfl(myid, i2);
        int b3 = __shfl(myid, i3);
        uint2 u0 = *(const uint2*)(h16 + (size_t)b0 * DD + cl * 4);
        uint2 u1 = *(const uint2*)(h16 + (size_t)b1 * DD + cl * 4);
        uint2 u2 = *(const uint2*)(h16 + (size_t)b2 * DD + cl * 4);
        uint2 u3 = *(const uint2*)(h16 + (size_t)b3 * DD + cl * 4);
        if (i0 < kk) { float2 f0 = __half22float2(*(__half2*)&u0.x), f1 = __half22float2(*(__half2*)&u0.y);
                       s0 += f0.x; s1 += f0.y; s2 += f1.x; s3 += f1.y; }
        if (i1 < kk) { float2 f0 = __half22float2(*(__half2*)&u1.x), f1 = __half22float2(*(__half2*)&u1.y);
                       s0 += f0.x; s1 += f0.y; s2 += f1.x; s3 += f1.y; }
        if (i2 < kk) { float2 f0 = __half22float2(*(__half2*)&u2.x), f1 = __half22float2(*(__half2*)&u2.y);
                       s0 += f0.x; s1 += f0.y; s2 += f1.x; s3 += f1.y; }
        if (i3 < kk) { float2 f0 = __half22float2(*(__half2*)&u3.x), f1 = __half22float2(*(__half2*)&u3.y);
                       s0 += f0.x; s1 += f0.y; s2 += f1.x; s3 += f1.y; }
    }

    int nov = *ovn;
    if (nov > 0 && sub == 0) {
        if (nov > OVCAP) nov = OVCAP;
        for (int i = 0; i < nov; i++) {
            int2 p = ov[i];
            if (p.x == node) {
                uint2 u = *(const uint2*)(h16 + (size_t)p.y * DD + cl * 4);
                float2 f0 = __half22float2(*(__half2*)&u.x), f1 = __half22float2(*(__half2*)&u.y);
                s0 += f0.x; s1 += f0.y; s2 += f1.x; s3 += f1.y;
            }
        }
    }

    s0 += __shfl_xor(s0, 16); s1 += __shfl_xor(s1, 16);
    s2 += __shfl_xor(s2, 16); s3 += __shfl_xor(s3, 16);
    s0 += __shfl_xor(s0, 32); s1 += __shfl_xor(s1, 32);
    s2 += __shfl_xor(s2, 32); s3 += __shfl_xor(s3, 32);

    if (sub == 0) {
        float inv = 1.0f / (float)(deg > 1 ? deg : 1);
        __half2 h0 = __floats2half2_rn(s0 * inv, s1 * inv);
        __half2 h1 = __floats2half2_rn(s2 * inv, s3 * inv);
        uint2 pk; pk.x = *(u32*)&h0; pk.y = *(u32*)&h1;
        *(uint2*)(agg16 + (size_t)node * DD + cl * 4) = pk;
    }
}

// ---- dense part: out = agg @ Wl^T + bl + h @ Wr^T (+ReLU) ----
// 512 threads = 8 waves per 64-row block; j0 wave-uniform -> W (packed fp16
// pairs) rides the scalar pipe; v_dot2_f32_f16 inner loop; fp16 LDS tiles.
// LAST=0: fp16 out + ReLU | LAST=1: fp32 out, no ReLU
template<int LAST>
__global__ __launch_bounds__(512) void k_gemm(const u16* __restrict__ h16,
                                              const u16* __restrict__ agg16,
                                              const u32* __restrict__ Whl,
                                              const float* __restrict__ bl,
                                              const u32* __restrict__ Whr,
                                              u16* __restrict__ out16,
                                              float* __restrict__ out32)
{
    __shared__ u32 xt[64 * LROW];   // fp16 pairs, row stride 132 B
    __shared__ u32 at[64 * LROW];
    int t = threadIdx.x;
    int r0 = blockIdx.x * 64;

    {
        int r = t >> 3, c8 = t & 7;
        int row = r0 + r;
        uint4 ux = make_uint4(0, 0, 0, 0), ua = ux;
        if (row < NN) {
            ux = *(const uint4*)(h16  + (size_t)row * DD + c8 * 8);
            ua = *(const uint4*)(agg16 + (size_t)row * DD + c8 * 8);
        }
        u32* px = &xt[r * LROW + c8 * 4];
        px[0] = ux.x; px[1] = ux.y; px[2] = ux.z; px[3] = ux.w;
        u32* pa = &at[r * LROW + c8 * 4];
        pa[0] = ua.x; pa[1] = ua.y; pa[2] = ua.z; pa[3] = ua.w;
    }
    __syncthreads();

    int row = t & 63;
    int j0 = __builtin_amdgcn_readfirstlane((t >> 6) * 8);   // wave-uniform SGPR
    float acc[8];
    #pragma unroll
    for (int q = 0; q < 8; q++) acc[q] = bl[j0 + q];

    #pragma unroll 4
    for (int k2 = 0; k2 < 32; k2++) {
        u32 aw = at[row * LROW + k2];
        u32 xw = xt[row * LROW + k2];
        #pragma unroll
        for (int q = 0; q < 8; q++) {
            acc[q] = dot2(aw, Whl[(j0 + q) * 32 + k2],
                     dot2(xw, Whr[(j0 + q) * 32 + k2], acc[q]));
        }
    }

    int grow = r0 + row;
    if (grow < NN) {
        if (LAST == 0) {
            #pragma unroll
            for (int q = 0; q < 8; q++) acc[q] = fmaxf(acc[q], 0.f);
            u32 w[4];
            #pragma unroll
            for (int p = 0; p < 4; p++) {
                __half2 hv = __floats2half2_rn(acc[2 * p], acc[2 * p + 1]);
                w[p] = *(u32*)&hv;
            }
            *(uint4*)(out16 + (size_t)grow * DD + j0) = make_uint4(w[0], w[1], w[2], w[3]);
        } else {
            float4* o = (float4*)(out32 + (size_t)grow * DD + j0);
            o[0] = make_float4(acc[0], acc[1], acc[2], acc[3]);
            o[1] = make_float4(acc[4], acc[5], acc[6], acc[7]);
        }
    }
}

extern "C" void kernel_launch(void* const* d_in, const int* in_sizes, int n_in,
                              void* d_out, int out_size, void* d_ws, size_t ws_size,
                              hipStream_t stream) {
    const float* x   = (const float*)d_in[0];
    const int*   ei  = (const int*)d_in[1];
    const int*   src = ei;            // edge_index[0]
    const int*   dst = ei + NE;       // edge_index[1]
    const float* Wl0 = (const float*)d_in[2];
    const float* bl0 = (const float*)d_in[3];
    const float* Wr0 = (const float*)d_in[4];
    const float* Wl1 = (const float*)d_in[5];
    const float* bl1 = (const float*)d_in[6];
    const float* Wr1 = (const float*)d_in[7];
    const float* Wl2 = (const float*)d_in[8];
    const float* bl2 = (const float*)d_in[9];
    const float* Wr2 = (const float*)d_in[10];
    float* out = (float*)d_out;

    char* ws = (char*)d_ws;
    size_t o = 0;
    u16*   h16A   = (u16*)(ws + o);   o += (size_t)NN * DD * 2;        // 6.4 MB
    u16*   h16B   = (u16*)(ws + o);   o += (size_t)NN * DD * 2;        // 6.4 MB
    u16*   agg16  = (u16*)(ws + o);   o += (size_t)NN * DD * 2;        // 6.4 MB
    u16*   bucket = (u16*)(ws + o);   o += (size_t)NN * BCAP * 2;      // 6.4 MB
    u32*   sorted = (u32*)(ws + o);   o += (size_t)NBINS * SEGCAP * 4; // 3.6 MB
    int*   deg    = (int*)(ws + o);   o += (size_t)NN * 4;             // 200 KB
    u32*   Wh     = (u32*)(ws + o);   o += (size_t)6 * 2048 * 4;       // 48 KB
    int*   seg_cnt= (int*)(ws + o);   o += (size_t)NBINS * SEGPAD * 4; // 12.5 KB
    int*   ovn    = (int*)(ws + o);   o += 16;                         // adjacent
    int2*  ov     = (int2*)(ws + o);  o += (size_t)OVCAP * 8;          // 32 KB

    // ---- prep: zero seg_cnt+ovn; partition edges; build buckets ----
    hipMemsetAsync(seg_cnt, 0, (size_t)NBINS * SEGPAD * 4 + 16, stream);
    k_part<<<PB + WB + CG, 256, 0, stream>>>(src, dst, seg_cnt, sorted, ovn, ov,
                                             x, h16B, Wl0, Wr0, Wl1, Wr1, Wl2, Wr2, Wh);
    k_bucket<<<NBINS, 256, 0, stream>>>(seg_cnt, sorted, bucket, deg, ovn, ov);

    const int ag = NN / 4;           // 12500: one wave per node
    const int gg = (NN + 63) / 64;   // 782

    // layer 0: h16B(x) -> h16A (ReLU)
    k_agg<<<ag, 256, 0, stream>>>(h16B, deg, bucket, ovn, ov, agg16);
    k_gemm<0><<<gg, 512, 0, stream>>>(h16B, agg16, Wh + 0 * 2048, bl0, Wh + 1 * 2048, h16A, nullptr);
    // layer 1: h16A -> h16B (ReLU)
    k_agg<<<ag, 256, 0, stream>>>(h16A, deg, bucket, ovn, ov, agg16);
    k_gemm<0><<<gg, 512, 0, stream>>>(h16A, agg16, Wh + 2 * 2048, bl1, Wh + 3 * 2048, h16B, nullptr);
    // layer 2: h16B -> out fp32 (no ReLU)
    k_agg<<<ag, 256, 0, stream>>>(h16B, deg, bucket, ovn, ov, agg16);
    k_gemm<1><<<gg, 512, 0, stream>>>(h16B, agg16, Wh + 4 * 2048, bl2, Wh + 5 * 2048, nullptr, out);
}

// Round 13
// 127.024 us; speedup vs baseline: 2.4270x; 1.0536x over previous
//
#include <hip/hip_runtime.h>
#include <hip/hip_fp16.h>

#define NN 50000
#define NE 800000
#define DD 64
#define BCAP 64        // bucket capacity per node (Poisson(16): P(>64) ~ 1e-19)
#define OVCAP 4096     // overflow list capacity
#define NBINS 196      // ceil(NN/256): bin = dst >> 8 (256 nodes per bin)
#define SEGCAP 4608    // per-bin segment capacity (mean 4082 + ~8 sigma)
#define PB 391         // partition blocks: ceil(NE / 2048)
#define EPB 2048       // edges per partition block
#define WB 12          // W fp16-pack blocks (6 mats x 2048 u32 / (256*4))
#define CG 3125        // tohalf blocks: NN*DD/4 / 256
#define LROW 33        // LDS row stride in u32 (132 B: conflict-free column reads)
#define SEGPAD 16      // seg_cnt stride in ints (one 64B line per bin)

typedef unsigned short u16;
typedef unsigned int u32;

// packed fp16x2 dot with f32 accumulate; hardware v_dot2_f32_f16 when available
__device__ __forceinline__ float dot2(u32 a, u32 b, float c) {
#if __has_builtin(__builtin_amdgcn_fdot2)
    typedef _Float16 h2 __attribute__((ext_vector_type(2)));
    h2 av, bv;
    __builtin_memcpy(&av, &a, 4);
    __builtin_memcpy(&bv, &b, 4);
    return __builtin_amdgcn_fdot2(av, bv, c, false);
#else
    float2 af = __half22float2(*(__half2*)&a);
    float2 bf = __half22float2(*(__half2*)&b);
    return fmaf(af.x, bf.x, fmaf(af.y, bf.y, c));
#endif
}

// ---- P2: partition edges into 256-node bins via LDS histogram + line-padded
//      chunk reservation. Extra blocks: W fp16-pack, then x -> fp16 convert. ----
__global__ __launch_bounds__(256) void k_part(const int* __restrict__ src,
                                              const int* __restrict__ dst,
                                              int* __restrict__ seg_cnt,
                                              u32* __restrict__ sorted,
                                              int* __restrict__ ovn,
                                              int2* __restrict__ ov,
                                              const float* __restrict__ x,
                                              u16* __restrict__ xh,
                                              const float* __restrict__ Wl0,
                                              const float* __restrict__ Wr0,
                                              const float* __restrict__ Wl1,
                                              const float* __restrict__ Wr1,
                                              const float* __restrict__ Wl2,
                                              const float* __restrict__ Wr2,
                                              u32* __restrict__ Wh) {
    int t = threadIdx.x;
    if (blockIdx.x >= PB + WB) {              // ---- x -> fp16 convert ----
        int i = (blockIdx.x - PB - WB) * 256 + t;
        if (i < NN * DD / 4) {
            float4 v = ((const float4*)x)[i];
            __half2 h01 = __floats2half2_rn(v.x, v.y);
            __half2 h23 = __floats2half2_rn(v.z, v.w);
            uint2 pk;
            pk.x = *(u32*)&h01; pk.y = *(u32*)&h23;
            ((uint2*)xh)[i] = pk;
        }
        return;
    }
    if (blockIdx.x >= PB) {                   // ---- W fp32 -> packed fp16 pairs ----
        int widx = (blockIdx.x - PB) * 256 + t;
        #pragma unroll
        for (int r = 0; r < 4; r++) {
            int oi = widx + r * (WB * 256);
            if (oi < 6 * 2048) {
                int mat = oi >> 11, rem = oi & 2047;
                const float* Wsrc;
                switch (mat) {
                    case 0: Wsrc = Wl0; break;
                    case 1: Wsrc = Wr0; break;
                    case 2: Wsrc = Wl1; break;
                    case 3: Wsrc = Wr1; break;
                    case 4: Wsrc = Wl2; break;
                    default: Wsrc = Wr2; break;
                }
                __half2 hv = __floats2half2_rn(Wsrc[rem * 2], Wsrc[rem * 2 + 1]);
                Wh[oi] = *(u32*)&hv;
            }
        }
        return;
    }
    // ---- edge partition ----
    __shared__ int hist[NBINS];
    int base_e = blockIdx.x * EPB;
    if (t < NBINS) hist[t] = 0;
    __syncthreads();
    #pragma unroll 4
    for (int r = 0; r < EPB / 256; r++) {     // pass A: block-local histogram
        int e = base_e + r * 256 + t;
        if (e < NE) atomicAdd(&hist[dst[e] >> 8], 1);
    }
    __syncthreads();
    if (t < NBINS) {                          // reserve chunk (1 line per bin)
        int c = hist[t];
        int b = (c > 0) ? atomicAdd(&seg_cnt[t * SEGPAD], c) : 0;
        hist[t] = b;
    }
    __syncthreads();
    #pragma unroll 4
    for (int r = 0; r < EPB / 256; r++) {     // pass B: scatter into chunks
        int e = base_e + r * 256 + t;
        if (e < NE) {
            int d = dst[e], s = src[e];
            int bin = d >> 8;
            int pos = atomicAdd(&hist[bin], 1);
            if (pos < SEGCAP) sorted[bin * SEGCAP + pos] = ((u32)(d & 255) << 16) | (u32)s;
            else { int q = atomicAdd(ovn, 1); if (q < OVCAP) ov[q] = make_int2(d, s); }
        }
    }
}

// ---- P4: per-bin bucket build. Contiguous segment read, 256-node LDS cursor,
//      localized bucket writes (32 KB node-region per block), degree output. ----
__global__ __launch_bounds__(256) void k_bucket(const int* __restrict__ seg_cnt,
                                                const u32* __restrict__ sorted,
                                                u16* __restrict__ bucket,
                                                int* __restrict__ deg,
                                                int* __restrict__ ovn,
                                                int2* __restrict__ ov) {
    int bin = blockIdx.x;
    int t = threadIdx.x;
    __shared__ int cur[256];
    cur[t] = 0;
    __syncthreads();
    int n = seg_cnt[bin * SEGPAD];
    if (n > SEGCAP) n = SEGCAP;
    for (int i = t; i < n; i += 256) {
        u32 w = sorted[bin * SEGCAP + i];
        int dl = (int)(w >> 16);
        int s  = (int)(w & 0xFFFF);
        int slot = atomicAdd(&cur[dl], 1);
        int node = (bin << 8) + dl;
        if (slot < BCAP) bucket[(size_t)node * BCAP + slot] = (u16)s;
        else { int q = atomicAdd(ovn, 1); if (q < OVCAP) ov[q] = make_int2(node, s); }
    }
    __syncthreads();
    int node = (bin << 8) + t;
    if (node < NN) deg[node] = cur[t];
}

// accumulate one fp16x4 row chunk (uint2) into 4 scalars, guarded
#define ACC1(U, COND, S0, S1, S2, S3)                                            \
    if (COND) { float2 f0 = __half22float2(*(__half2*)&U.x);                     \
                float2 f1 = __half22float2(*(__half2*)&U.y);                     \
                S0 += f0.x; S1 += f0.y; S2 += f1.x; S3 += f1.y; }

// ---- gather-aggregate (fp16 in, fp16 out): TWO nodes per wave ----
// 8 independent uint2 loads in flight per lane (4 per node, 16 nbrs/node/iter).
__global__ __launch_bounds__(256) void k_agg(const u16* __restrict__ h16,
                                             const int* __restrict__ deg_arr,
                                             const u16* __restrict__ bucket,
                                             const int* __restrict__ ovn,
                                             const int2* __restrict__ ov,
                                             u16* __restrict__ agg16) {
    int w = blockIdx.x * 4 + (threadIdx.x >> 6);   // wave id; 2 nodes per wave
    int nA = w * 2, nB = nA + 1;                   // grid covers NN exactly
    int l = threadIdx.x & 63;
    int sub = l >> 4;          // neighbor sub-group 0..3
    int cl = l & 15;           // 4-col block 0..15
    int degA = deg_arr[nA], degB = deg_arr[nB];
    int kkA = degA < BCAP ? degA : BCAP;
    int kkB = degB < BCAP ? degB : BCAP;
    int idA = (l < kkA) ? (int)bucket[(size_t)nA * BCAP + l] : 0;
    int idB = (l < kkB) ? (int)bucket[(size_t)nB * BCAP + l] : 0;

    float a0 = 0.f, a1 = 0.f, a2 = 0.f, a3 = 0.f;
    float b0 = 0.f, b1 = 0.f, b2 = 0.f, b3 = 0.f;
    int kmax = kkA > kkB ? kkA : kkB;
    for (int j = 0; j < kmax; j += 16) {
        int i0 = j + sub, i1 = j + 4 + sub, i2 = j + 8 + sub, i3 = j + 12 + sub;
        int nA0 = __shfl(idA, i0), nA1 = __shfl(idA, i1);
        int nA2 = __shfl(idA, i2), nA3 = __shfl(idA, i3);
        int nB0 = __shfl(idB, i0), nB1 = __shfl(idB, i1);
        int nB2 = __shfl(idB, i2), nB3 = __shfl(idB, i3);
        uint2 uA0 = *(const uint2*)(h16 + (size_t)nA0 * DD + cl * 4);
        uint2 uA1 = *(const uint2*)(h16 + (size_t)nA1 * DD + cl * 4);
        uint2 uA2 = *(const uint2*)(h16 + (size_t)nA2 * DD + cl * 4);
        uint2 uA3 = *(const uint2*)(h16 + (size_t)nA3 * DD + cl * 4);
        uint2 uB0 = *(const uint2*)(h16 + (size_t)nB0 * DD + cl * 4);
        uint2 uB1 = *(const uint2*)(h16 + (size_t)nB1 * DD + cl * 4);
        uint2 uB2 = *(const uint2*)(h16 + (size_t)nB2 * DD + cl * 4);
        uint2 uB3 = *(const uint2*)(h16 + (size_t)nB3 * DD + cl * 4);
        ACC1(uA0, i0 < kkA, a0, a1, a2, a3)
        ACC1(uA1, i1 < kkA, a0, a1, a2, a3)
        ACC1(uA2, i2 < kkA, a0, a1, a2, a3)
        ACC1(uA3, i3 < kkA, a0, a1, a2, a3)
        ACC1(uB0, i0 < kkB, b0, b1, b2, b3)
        ACC1(uB1, i1 < kkB, b0, b1, b2, b3)
        ACC1(uB2, i2 < kkB, b0, b1, b2, b3)
        ACC1(uB3, i3 < kkB, b0, b1, b2, b3)
    }

    // overflow contributions (empty in practice -> one uniform scalar check)
    int nov = *ovn;
    if (nov > 0) {
        if (nov > OVCAP) nov = OVCAP;
        for (int i = 0; i < nov; i++) {
            int2 p = ov[i];
            bool mA = (sub == 0) && (p.x == nA);
            bool mB = (sub == 1) && (p.x == nB);
            if (mA | mB) {
                uint2 u = *(const uint2*)(h16 + (size_t)p.y * DD + cl * 4);
                float2 f0 = __half22float2(*(__half2*)&u.x), f1 = __half22float2(*(__half2*)&u.y);
                if (mA) { a0 += f0.x; a1 += f0.y; a2 += f1.x; a3 += f1.y; }
                else    { b0 += f0.x; b1 += f0.y; b2 += f1.x; b3 += f1.y; }
            }
        }
    }

    // butterfly across the 4 sub-groups (both nodes)
    a0 += __shfl_xor(a0, 16); a1 += __shfl_xor(a1, 16);
    a2 += __shfl_xor(a2, 16); a3 += __shfl_xor(a3, 16);
    a0 += __shfl_xor(a0, 32); a1 += __shfl_xor(a1, 32);
    a2 += __shfl_xor(a2, 32); a3 += __shfl_xor(a3, 32);
    b0 += __shfl_xor(b0, 16); b1 += __shfl_xor(b1, 16);
    b2 += __shfl_xor(b2, 16); b3 += __shfl_xor(b3, 16);
    b0 += __shfl_xor(b0, 32); b1 += __shfl_xor(b1, 32);
    b2 += __shfl_xor(b2, 32); b3 += __shfl_xor(b3, 32);

    // sub 0 writes node A's row, sub 1 writes node B's row (parallel)
    if (sub == 0) {
        float inv = 1.0f / (float)(degA > 1 ? degA : 1);
        __half2 h0 = __floats2half2_rn(a0 * inv, a1 * inv);
        __half2 h1 = __floats2half2_rn(a2 * inv, a3 * inv);
        uint2 pk; pk.x = *(u32*)&h0; pk.y = *(u32*)&h1;
        *(uint2*)(agg16 + (size_t)nA * DD + cl * 4) = pk;
    } else if (sub == 1) {
        float inv = 1.0f / (float)(degB > 1 ? degB : 1);
        __half2 h0 = __floats2half2_rn(b0 * inv, b1 * inv);
        __half2 h1 = __floats2half2_rn(b2 * inv, b3 * inv);
        uint2 pk; pk.x = *(u32*)&h0; pk.y = *(u32*)&h1;
        *(uint2*)(agg16 + (size_t)nB * DD + cl * 4) = pk;
    }
}

// ---- dense part: out = agg @ Wl^T + bl + h @ Wr^T (+ReLU) ----
// 512 threads = 8 waves per 64-row block; j0 wave-uniform -> W (packed fp16
// pairs) rides the scalar pipe; v_dot2_f32_f16 inner loop; fp16 LDS tiles.
// LAST=0: fp16 out + ReLU | LAST=1: fp32 out, no ReLU
template<int LAST>
__global__ __launch_bounds__(512) void k_gemm(const u16* __restrict__ h16,
                                              const u16* __restrict__ agg16,
                                              const u32* __restrict__ Whl,
                                              const float* __restrict__ bl,
                                              const u32* __restrict__ Whr,
                                              u16* __restrict__ out16,
                                              float* __restrict__ out32)
{
    __shared__ u32 xt[64 * LROW];   // fp16 pairs, row stride 132 B
    __shared__ u32 at[64 * LROW];
    int t = threadIdx.x;
    int r0 = blockIdx.x * 64;

    {
        int r = t >> 3, c8 = t & 7;
        int row = r0 + r;
        uint4 ux = make_uint4(0, 0, 0, 0), ua = ux;
        if (row < NN) {
            ux = *(const uint4*)(h16  + (size_t)row * DD + c8 * 8);
            ua = *(const uint4*)(agg16 + (size_t)row * DD + c8 * 8);
        }
        u32* px = &xt[r * LROW + c8 * 4];
        px[0] = ux.x; px[1] = ux.y; px[2] = ux.z; px[3] = ux.w;
        u32* pa = &at[r * LROW + c8 * 4];
        pa[0] = ua.x; pa[1] = ua.y; pa[2] = ua.z; pa[3] = ua.w;
    }
    __syncthreads();

    int row = t & 63;
    int j0 = __builtin_amdgcn_readfirstlane((t >> 6) * 8);   // wave-uniform SGPR
    float acc[8];
    #pragma unroll
    for (int q = 0; q < 8; q++) acc[q] = bl[j0 + q];

    #pragma unroll 4
    for (int k2 = 0; k2 < 32; k2++) {
        u32 aw = at[row * LROW + k2];
        u32 xw = xt[row * LROW + k2];
        #pragma unroll
        for (int q = 0; q < 8; q++) {
            acc[q] = dot2(aw, Whl[(j0 + q) * 32 + k2],
                     dot2(xw, Whr[(j0 + q) * 32 + k2], acc[q]));
        }
    }

    int grow = r0 + row;
    if (grow < NN) {
        if (LAST == 0) {
            #pragma unroll
            for (int q = 0; q < 8; q++) acc[q] = fmaxf(acc[q], 0.f);
            u32 w[4];
            #pragma unroll
            for (int p = 0; p < 4; p++) {
                __half2 hv = __floats2half2_rn(acc[2 * p], acc[2 * p + 1]);
                w[p] = *(u32*)&hv;
            }
            *(uint4*)(out16 + (size_t)grow * DD + j0) = make_uint4(w[0], w[1], w[2], w[3]);
        } else {
            float4* o = (float4*)(out32 + (size_t)grow * DD + j0);
            o[0] = make_float4(acc[0], acc[1], acc[2], acc[3]);
            o[1] = make_float4(acc[4], acc[5], acc[6], acc[7]);
        }
    }
}

extern "C" void kernel_launch(void* const* d_in, const int* in_sizes, int n_in,
                              void* d_out, int out_size, void* d_ws, size_t ws_size,
                              hipStream_t stream) {
    const float* x   = (const float*)d_in[0];
    const int*   ei  = (const int*)d_in[1];
    const int*   src = ei;            // edge_index[0]
    const int*   dst = ei + NE;       // edge_index[1]
    const float* Wl0 = (const float*)d_in[2];
    const float* bl0 = (const float*)d_in[3];
    const float* Wr0 = (const float*)d_in[4];
    const float* Wl1 = (const float*)d_in[5];
    const float* bl1 = (const float*)d_in[6];
    const float* Wr1 = (const float*)d_in[7];
    const float* Wl2 = (const float*)d_in[8];
    const float* bl2 = (const float*)d_in[9];
    const float* Wr2 = (const float*)d_in[10];
    float* out = (float*)d_out;

    char* ws = (char*)d_ws;
    size_t o = 0;
    u16*   h16A   = (u16*)(ws + o);   o += (size_t)NN * DD * 2;        // 6.4 MB
    u16*   h16B   = (u16*)(ws + o);   o += (size_t)NN * DD * 2;        // 6.4 MB
    u16*   agg16  = (u16*)(ws + o);   o += (size_t)NN * DD * 2;        // 6.4 MB
    u16*   bucket = (u16*)(ws + o);   o += (size_t)NN * BCAP * 2;      // 6.4 MB
    u32*   sorted = (u32*)(ws + o);   o += (size_t)NBINS * SEGCAP * 4; // 3.6 MB
    int*   deg    = (int*)(ws + o);   o += (size_t)NN * 4;             // 200 KB
    u32*   Wh     = (u32*)(ws + o);   o += (size_t)6 * 2048 * 4;       // 48 KB
    int*   seg_cnt= (int*)(ws + o);   o += (size_t)NBINS * SEGPAD * 4; // 12.5 KB
    int*   ovn    = (int*)(ws + o);   o += 16;                         // adjacent
    int2*  ov     = (int2*)(ws + o);  o += (size_t)OVCAP * 8;          // 32 KB

    // ---- prep: zero seg_cnt+ovn; partition edges; build buckets ----
    hipMemsetAsync(seg_cnt, 0, (size_t)NBINS * SEGPAD * 4 + 16, stream);
    k_part<<<PB + WB + CG, 256, 0, stream>>>(src, dst, seg_cnt, sorted, ovn, ov,
                                             x, h16B, Wl0, Wr0, Wl1, Wr1, Wl2, Wr2, Wh);
    k_bucket<<<NBINS, 256, 0, stream>>>(seg_cnt, sorted, bucket, deg, ovn, ov);

    const int ag = NN / 8;           // 6250: two nodes per wave
    const int gg = (NN + 63) / 64;   // 782

    // layer 0: h16B(x) -> h16A (ReLU)
    k_agg<<<ag, 256, 0, stream>>>(h16B, deg, bucket, ovn, ov, agg16);
    k_gemm<0><<<gg, 512, 0, stream>>>(h16B, agg16, Wh + 0 * 2048, bl0, Wh + 1 * 2048, h16A, nullptr);
    // layer 1: h16A -> h16B (ReLU)
    k_agg<<<ag, 256, 0, stream>>>(h16A, deg, bucket, ovn, ov, agg16);
    k_gemm<0><<<gg, 512, 0, stream>>>(h16A, agg16, Wh + 2 * 2048, bl1, Wh + 3 * 2048, h16B, nullptr);
    // layer 2: h16B -> out fp32 (no ReLU)
    k_agg<<<ag, 256, 0, stream>>>(h16B, deg, bucket, ovn, ov, agg16);
    k_gemm<1><<<gg, 512, 0, stream>>>(h16B, agg16, Wh + 4 * 2048, bl2, Wh + 5 * 2048, nullptr, out);
}